// Round 5
// baseline (1955.930 us; speedup 1.0000x reference)
//
#include <hip/hip_runtime.h>
#include <stdint.h>

typedef __bf16 bf16x8 __attribute__((ext_vector_type(8)));
typedef float  f32x4  __attribute__((ext_vector_type(4)));

#define PRED   200
#define TSTEPS 200
#define NBLK   256
#define ASTR   280               // A-row stride in elems
#define ALO    136               // lo-plane column offset within a row
#define ABUFB  (16*ASTR*2)       // 8960 B per A buffer
#define W_BYTES 131072           // 128 frags x 64 lanes x 16B
#define A_OFF   W_BYTES
#define LDS_A   (A_OFF + 2*ABUFB)            // 148992
#define STG_OFF (A_OFF + 2*ABUFB)
#define LDS_C   (STG_OFF + ABUFB)            // 157952
#define CP_OFF  (A_OFF + 2*ABUFB)
#define CUR_OFF (CP_OFF + 1024)
#define LDS_D   (CUR_OFF + 128)              // 150144

// ws layout: [ stage: chunkLen*NBLK*2048 fp32 ][ state: NBLK*4*2048 fp32 ]
// state planes per block: 0=h0, 1=c0, 2=h1, 3=c1
#define STATE_FLOATS ((size_t)NBLK*4*2048)

__device__ __forceinline__ float sigm(float x){ return 1.0f/(1.0f+__expf(-x)); }
__device__ __forceinline__ float tanhx(float x){
  float t=__expf(-2.0f*fabsf(x)); float y=(1.0f-t)/(1.0f+t); return copysignf(y,x);
}
__device__ __forceinline__ bf16x8 hi8(float4 a, float4 b){
  bf16x8 r; r[0]=(__bf16)a.x; r[1]=(__bf16)a.y; r[2]=(__bf16)a.z; r[3]=(__bf16)a.w;
  r[4]=(__bf16)b.x; r[5]=(__bf16)b.y; r[6]=(__bf16)b.z; r[7]=(__bf16)b.w; return r;
}
__device__ __forceinline__ bf16x8 lo8(float4 a, float4 b, bf16x8 h){
  bf16x8 r;
  r[0]=(__bf16)(a.x-(float)h[0]); r[1]=(__bf16)(a.y-(float)h[1]);
  r[2]=(__bf16)(a.z-(float)h[2]); r[3]=(__bf16)(a.w-(float)h[3]);
  r[4]=(__bf16)(b.x-(float)h[4]); r[5]=(__bf16)(b.y-(float)h[5]);
  r[6]=(__bf16)(b.z-(float)h[6]); r[7]=(__bf16)(b.w-(float)h[7]); return r;
}
#define MFMA(A,B,C) __builtin_amdgcn_mfma_f32_16x16x32_bf16((A),(B),(C),0,0,0)

// ======================= layer-0 recurrent (per T-chunk) =======================
__global__ void __launch_bounds__(512,2)
k_l0(const float* __restrict__ xh, const float* __restrict__ wih0,
     const float* __restrict__ whh0, const float* __restrict__ bih0,
     const float* __restrict__ bhh0, float* __restrict__ wsf,
     int chunkStart, int chunkLen, unsigned long long stageFloats)
{
  extern __shared__ char smem[];
  const int tid=threadIdx.x, wv=tid>>6, l=tid&63, c=l&15, qd=l>>4;
  const int hc=wv*16+c, blk=blockIdx.x, r0=blk*16;
  float* stf = wsf + stageFloats;   // state planes
  #pragma unroll
  for (int i=0;i<16;++i){                    // cook W_hh0 hi -> LDS frag-linear
    int f=i*8+wv, ntg=f>>2, kt=f&3;
    int g=(ntg&3)*128+(ntg>>2)*16+c, k=kt*32+qd*8;
    const float* s=whh0+g*128+k;
    *(bf16x8*)(smem+f*1024+l*16)=hi8(*(const float4*)s,*(const float4*)(s+4));
  }
  bf16x8 wlo[16];
  #pragma unroll
  for (int tt=0;tt<4;++tt)
    #pragma unroll
    for (int kt=0;kt<4;++kt){
      const float* s=whh0+(size_t)(tt*128+hc)*128+kt*32+qd*8;
      float4 a=*(const float4*)s, b=*(const float4*)(s+4);
      wlo[tt*4+kt]=lo8(a,b,hi8(a,b));
    }
  float b0[4], w0x[4], w0y[4];
  #pragma unroll
  for (int tt=0;tt<4;++tt){
    int g=tt*128+hc;
    b0[tt]=bih0[g]+bhh0[g]; w0x[tt]=wih0[2*g]; w0y[tt]=wih0[2*g+1];
  }
  float c0[4];
  {
    __bf16* B1=(__bf16*)(smem+A_OFF+ABUFB);
    const float* hst=stf+(size_t)(blk*4+0)*2048;
    const float* cst=stf+(size_t)(blk*4+1)*2048;
    #pragma unroll
    for (int i=0;i<4;++i){
      int e=tid*4+i, row=e>>7, col=e&127;
      float v=0.f; if(chunkStart) v=hst[e];
      __bf16 h=(__bf16)v;
      B1[row*ASTR+col]=h; B1[row*ASTR+ALO+col]=(__bf16)(v-(float)h);
    }
    #pragma unroll
    for (int j=0;j<4;++j){ float v=0.f; if(chunkStart) v=cst[(qd*4+j)*128+hc]; c0[j]=v; }
  }
  __syncthreads();
  for (int t=0;t<chunkLen;++t){
    const int p=t&1, tg=chunkStart+t;
    float2 xv[4];
    #pragma unroll
    for (int j=0;j<4;++j) xv[j]=*(const float2*)(xh+(size_t)(r0+qd*4+j)*400+tg*2);
    f32x4 acc[4];
    #pragma unroll
    for (int tt=0;tt<4;++tt) acc[tt]=(f32x4){b0[tt],b0[tt],b0[tt],b0[tt]};
    const char* Ar=smem+A_OFF+(size_t)(1-p)*ABUFB;
    #pragma unroll
    for (int kt=0;kt<4;++kt){
      bf16x8 ah=*(const bf16x8*)(Ar+(c*ASTR+kt*32+qd*8)*2);
      bf16x8 al=*(const bf16x8*)(Ar+(c*ASTR+ALO+kt*32+qd*8)*2);
      #pragma unroll
      for (int tt=0;tt<4;++tt){
        bf16x8 bh=*(const bf16x8*)(smem+(size_t)((wv*4+tt)*4+kt)*1024+l*16);
        acc[tt]=MFMA(ah,bh,acc[tt]);
        acc[tt]=MFMA(al,bh,acc[tt]);
        acc[tt]=MFMA(ah,wlo[tt*4+kt],acc[tt]);
      }
    }
    __bf16* Aw=(__bf16*)(smem+A_OFF+(size_t)p*ABUFB);
    float* h0o=wsf+((size_t)t*NBLK+blk)*2048;
    #pragma unroll
    for (int j=0;j<4;++j){
      float gi=acc[0][j]+xv[j].x*w0x[0]+xv[j].y*w0y[0];
      float gf=acc[1][j]+xv[j].x*w0x[1]+xv[j].y*w0y[1];
      float gg=acc[2][j]+xv[j].x*w0x[2]+xv[j].y*w0y[2];
      float go=acc[3][j]+xv[j].x*w0x[3]+xv[j].y*w0y[3];
      float cn=sigm(gf)*c0[j]+sigm(gi)*tanhx(gg); c0[j]=cn;
      float hn=sigm(go)*tanhx(cn);
      int row=qd*4+j;
      __bf16 hh=(__bf16)hn;
      Aw[row*ASTR+hc]=hh; Aw[row*ASTR+ALO+hc]=(__bf16)(hn-(float)hh);
      h0o[row*128+hc]=hn;
      if (t==chunkLen-1){
        stf[(size_t)(blk*4+0)*2048+row*128+hc]=hn;
        stf[(size_t)(blk*4+1)*2048+row*128+hc]=cn;
      }
    }
    __syncthreads();
  }
}

// ======================= layer-1 recurrent (per T-chunk) =======================
__global__ void __launch_bounds__(512,2)
k_l1(const float* __restrict__ wih1, const float* __restrict__ whh1,
     const float* __restrict__ bih1, const float* __restrict__ bhh1,
     float* __restrict__ wsf, int chunkStart, int chunkLen,
     unsigned long long stageFloats)
{
  extern __shared__ char smem[];
  const int tid=threadIdx.x, wv=tid>>6, l=tid&63, c=l&15, qd=l>>4;
  const int hc=wv*16+c, blk=blockIdx.x;
  float* stf = wsf + stageFloats;
  #pragma unroll
  for (int i=0;i<16;++i){                    // cook W_ih1 hi -> LDS
    int f=i*8+wv, ntg=f>>2, kt=f&3;
    int g=(ntg&3)*128+(ntg>>2)*16+c, k=kt*32+qd*8;
    const float* s=wih1+g*128+k;
    *(bf16x8*)(smem+f*1024+l*16)=hi8(*(const float4*)s,*(const float4*)(s+4));
  }
  bf16x8 whh[16], whl[16];
  #pragma unroll
  for (int tt=0;tt<4;++tt)
    #pragma unroll
    for (int kt=0;kt<4;++kt){
      const float* s2=whh1+(size_t)(tt*128+hc)*128+kt*32+qd*8;
      float4 a2=*(const float4*)s2, b2=*(const float4*)(s2+4);
      bf16x8 h2=hi8(a2,b2);
      whh[tt*4+kt]=h2; whl[tt*4+kt]=lo8(a2,b2,h2);
    }
  float b1v[4];
  #pragma unroll
  for (int tt=0;tt<4;++tt){ int g=tt*128+hc; b1v[tt]=bih1[g]+bhh1[g]; }
  float c1[4];
  {
    __bf16* B1=(__bf16*)(smem+A_OFF+ABUFB);
    const float* hst=stf+(size_t)(blk*4+2)*2048;
    const float* cst=stf+(size_t)(blk*4+3)*2048;
    #pragma unroll
    for (int i=0;i<4;++i){
      int e=tid*4+i, row=e>>7, col=e&127;
      float v=0.f; if(chunkStart) v=hst[e];
      __bf16 h=(__bf16)v;
      B1[row*ASTR+col]=h; B1[row*ASTR+ALO+col]=(__bf16)(v-(float)h);
    }
    #pragma unroll
    for (int j=0;j<4;++j){ float v=0.f; if(chunkStart) v=cst[(qd*4+j)*128+hc]; c1[j]=v; }
  }
  float4 r4=*(const float4*)(wsf+((size_t)0*NBLK+blk)*2048+tid*4);
  __syncthreads();
  for (int t=0;t<chunkLen;++t){
    const int p=t&1;
    {
      __bf16* ST=(__bf16*)(smem+STG_OFF);
      int e=tid*4, row=e>>7, col=e&127;
      #pragma unroll
      for (int i=0;i<4;++i){
        float v=r4[i]; __bf16 h=(__bf16)v;
        ST[row*ASTR+col+i]=h; ST[row*ASTR+ALO+col+i]=(__bf16)(v-(float)h);
      }
    }
    if (t+1<chunkLen) r4=*(const float4*)(wsf+((size_t)(t+1)*NBLK+blk)*2048+tid*4);
    __syncthreads();
    f32x4 acc[4];
    #pragma unroll
    for (int tt=0;tt<4;++tt) acc[tt]=(f32x4){b1v[tt],b1v[tt],b1v[tt],b1v[tt]};
    const char* Ar=smem+A_OFF+(size_t)(1-p)*ABUFB;
    const char* Sr=smem+STG_OFF;
    #pragma unroll
    for (int kt=0;kt<4;++kt){
      bf16x8 a0h=*(const bf16x8*)(Sr+(c*ASTR+kt*32+qd*8)*2);
      bf16x8 a0l=*(const bf16x8*)(Sr+(c*ASTR+ALO+kt*32+qd*8)*2);
      bf16x8 a1h=*(const bf16x8*)(Ar+(c*ASTR+kt*32+qd*8)*2);
      bf16x8 a1l=*(const bf16x8*)(Ar+(c*ASTR+ALO+kt*32+qd*8)*2);
      #pragma unroll
      for (int tt=0;tt<4;++tt){
        bf16x8 bh=*(const bf16x8*)(smem+(size_t)((wv*4+tt)*4+kt)*1024+l*16);
        // wih1 lo-plane recomputed on the fly (keeps VGPRs under 256)
        const float* sw=wih1+(size_t)(tt*128+hc)*128+kt*32+qd*8;
        float4 wa=*(const float4*)sw, wb=*(const float4*)(sw+4);
        bf16x8 wl=lo8(wa,wb,hi8(wa,wb));
        acc[tt]=MFMA(a0h,bh,acc[tt]);
        acc[tt]=MFMA(a0l,bh,acc[tt]);
        acc[tt]=MFMA(a0h,wl,acc[tt]);
        acc[tt]=MFMA(a1h,whh[tt*4+kt],acc[tt]);
        acc[tt]=MFMA(a1l,whh[tt*4+kt],acc[tt]);
        acc[tt]=MFMA(a1h,whl[tt*4+kt],acc[tt]);
      }
    }
    __bf16* Aw=(__bf16*)(smem+A_OFF+(size_t)p*ABUFB);
    #pragma unroll
    for (int j=0;j<4;++j){
      float cn=sigm(acc[1][j])*c1[j]+sigm(acc[0][j])*tanhx(acc[2][j]); c1[j]=cn;
      float hn=sigm(acc[3][j])*tanhx(cn);
      int row=qd*4+j;
      __bf16 hh=(__bf16)hn;
      Aw[row*ASTR+hc]=hh; Aw[row*ASTR+ALO+hc]=(__bf16)(hn-(float)hh);
      if (t==chunkLen-1){
        stf[(size_t)(blk*4+2)*2048+row*128+hc]=hn;
        stf[(size_t)(blk*4+3)*2048+row*128+hc]=cn;
      }
    }
    __syncthreads();
  }
}

// ======================= decoder (200 autoregressive steps) =======================
__global__ void __launch_bounds__(512,2)
k_dec(const float* __restrict__ xh, const float* __restrict__ pprm,
      const float* __restrict__ dwihp, const float* __restrict__ dwhh,
      const float* __restrict__ dbih, const float* __restrict__ dbhh,
      const float* __restrict__ pw, const float* __restrict__ pb,
      const float* __restrict__ ow, const float* __restrict__ ob,
      const float* __restrict__ wsf, float* __restrict__ out,
      unsigned long long stageFloats)
{
  extern __shared__ char smem[];
  const int tid=threadIdx.x, wv=tid>>6, l=tid&63, c=l&15, qd=l>>4;
  const int hc=wv*16+c, blk=blockIdx.x, r0=blk*16;
  const float* stf = wsf + stageFloats;
  #pragma unroll
  for (int i=0;i<16;++i){                    // cook dec_w_hh hi -> LDS
    int f=i*8+wv, ntg=f>>2, kt=f&3;
    int g=(ntg&3)*128+(ntg>>2)*16+c, k=kt*32+qd*8;
    const float* s=dwhh+g*128+k;
    *(bf16x8*)(smem+f*1024+l*16)=hi8(*(const float4*)s,*(const float4*)(s+4));
  }
  bf16x8 wlo[16];
  #pragma unroll
  for (int tt=0;tt<4;++tt)
    #pragma unroll
    for (int kt=0;kt<4;++kt){
      const float* s=dwhh+(size_t)(tt*128+hc)*128+kt*32+qd*8;
      float4 a=*(const float4*)s, b=*(const float4*)(s+4);
      wlo[tt*4+kt]=lo8(a,b,hi8(a,b));
    }
  float dwi[4][5], db[4];
  #pragma unroll
  for (int tt=0;tt<4;++tt){
    int g=tt*128+hc;
    db[tt]=dbih[g]+dbhh[g];
    #pragma unroll
    for (int k=0;k<5;++k) dwi[tt][k]=dwihp[g*5+k];
  }
  float prj0=pw[hc*3+0], prj1=pw[hc*3+1], prj2=pw[hc*3+2], prjb=pb[hc];
  float ow0=ow[hc], ow1=ow[128+hc];
  float prm[4][3];
  #pragma unroll
  for (int j=0;j<4;++j){
    size_t r=(size_t)(r0+qd*4+j);
    prm[j][0]=pprm[r*3+0]; prm[j][1]=pprm[r*3+1]; prm[j][2]=pprm[r*3+2];
  }
  const float* h1s=stf+(size_t)(blk*4+2)*2048;
  const float* c1s=stf+(size_t)(blk*4+3)*2048;
  float c1[4];
  {
    __bf16* B0=(__bf16*)(smem+A_OFF);
    #pragma unroll
    for (int j=0;j<4;++j){
      int row=qd*4+j;
      float hd=h1s[row*128+hc]+prm[j][0]*prj0+prm[j][1]*prj1+prm[j][2]*prj2+prjb;
      __bf16 h=(__bf16)hd;
      B0[row*ASTR+hc]=h; B0[row*ASTR+ALO+hc]=(__bf16)(hd-(float)h);
      c1[j]=c1s[row*128+hc];
    }
  }
  float obv=0.f;
  if (tid<32){
    int r=tid>>1, d=tid&1;
    ((float*)(smem+CUR_OFF))[tid]=xh[(size_t)(r0+r)*400+199*2+d];
    obv=ob[d];
  }
  __syncthreads();
  for (int s=0;s<PRED;++s){
    const int q=s&1;
    float cur0[4], cur1[4];
    #pragma unroll
    for (int j=0;j<4;++j){
      cur0[j]=((const float*)(smem+CUR_OFF))[(qd*4+j)*2+0];
      cur1[j]=((const float*)(smem+CUR_OFF))[(qd*4+j)*2+1];
    }
    f32x4 acc[4];
    #pragma unroll
    for (int tt=0;tt<4;++tt) acc[tt]=(f32x4){db[tt],db[tt],db[tt],db[tt]};
    const char* Ar=smem+A_OFF+(size_t)q*ABUFB;
    #pragma unroll
    for (int kt=0;kt<4;++kt){
      bf16x8 ah=*(const bf16x8*)(Ar+(c*ASTR+kt*32+qd*8)*2);
      bf16x8 al=*(const bf16x8*)(Ar+(c*ASTR+ALO+kt*32+qd*8)*2);
      #pragma unroll
      for (int tt=0;tt<4;++tt){
        bf16x8 bh=*(const bf16x8*)(smem+(size_t)((wv*4+tt)*4+kt)*1024+l*16);
        acc[tt]=MFMA(ah,bh,acc[tt]);
        acc[tt]=MFMA(al,bh,acc[tt]);
        acc[tt]=MFMA(ah,wlo[tt*4+kt],acc[tt]);
      }
    }
    __bf16* Aw=(__bf16*)(smem+A_OFF+(size_t)(1-q)*ABUFB);
    float pc0[4], pc1[4];
    #pragma unroll
    for (int j=0;j<4;++j){
      float gi=acc[0][j]+cur0[j]*dwi[0][0]+cur1[j]*dwi[0][1]+prm[j][0]*dwi[0][2]+prm[j][1]*dwi[0][3]+prm[j][2]*dwi[0][4];
      float gf=acc[1][j]+cur0[j]*dwi[1][0]+cur1[j]*dwi[1][1]+prm[j][0]*dwi[1][2]+prm[j][1]*dwi[1][3]+prm[j][2]*dwi[1][4];
      float gg=acc[2][j]+cur0[j]*dwi[2][0]+cur1[j]*dwi[2][1]+prm[j][0]*dwi[2][2]+prm[j][1]*dwi[2][3]+prm[j][2]*dwi[2][4];
      float go=acc[3][j]+cur0[j]*dwi[3][0]+cur1[j]*dwi[3][1]+prm[j][0]*dwi[3][2]+prm[j][1]*dwi[3][3]+prm[j][2]*dwi[3][4];
      float cn=sigm(gf)*c1[j]+sigm(gi)*tanhx(gg); c1[j]=cn;
      float hn=sigm(go)*tanhx(cn);
      int row=qd*4+j;
      __bf16 hh=(__bf16)hn;
      Aw[row*ASTR+hc]=hh; Aw[row*ASTR+ALO+hc]=(__bf16)(hn-(float)hh);
      pc0[j]=hn*ow0; pc1[j]=hn*ow1;
    }
    #pragma unroll
    for (int m=1;m<16;m<<=1){
      #pragma unroll
      for (int j=0;j<4;++j){
        pc0[j]+=__shfl_xor(pc0[j],m,64);
        pc1[j]+=__shfl_xor(pc1[j],m,64);
      }
    }
    float* cp=(float*)(smem+CP_OFF);
    if (c==0){
      #pragma unroll
      for (int j=0;j<4;++j){
        cp[(wv*16+qd*4+j)*2+0]=pc0[j];
        cp[(wv*16+qd*4+j)*2+1]=pc1[j];
      }
    }
    __syncthreads();
    if (tid<32){
      int r=tid>>1, d=tid&1;
      float sv=obv;
      #pragma unroll
      for (int w2=0;w2<8;++w2) sv+=cp[(w2*16+r)*2+d];
      ((float*)(smem+CUR_OFF))[tid]=sv;
      out[(size_t)(r0+r)*400+s*2+d]=sv;     // fp32 output — the fix
    }
    __syncthreads();
  }
}

extern "C" void kernel_launch(void* const* d_in, const int* in_sizes, int n_in,
                              void* d_out, int out_size, void* d_ws, size_t ws_size,
                              hipStream_t stream)
{
  (void)out_size;
  // binding: index 2 is pred_len (scalar, size 1) if present; otherwise weights start at 2
  const int base = (n_in >= 19 && in_sizes[2] == 1) ? 3 : 2;
  const float* xh   = (const float*)d_in[0];
  const float* prm  = (const float*)d_in[1];
  const float* wih0 = (const float*)d_in[base+0];
  const float* whh0 = (const float*)d_in[base+1];
  const float* bih0 = (const float*)d_in[base+2];
  const float* bhh0 = (const float*)d_in[base+3];
  const float* wih1 = (const float*)d_in[base+4];
  const float* whh1 = (const float*)d_in[base+5];
  const float* bih1 = (const float*)d_in[base+6];
  const float* bhh1 = (const float*)d_in[base+7];
  const float* dwih = (const float*)d_in[base+8];
  const float* dwhh = (const float*)d_in[base+9];
  const float* dbih = (const float*)d_in[base+10];
  const float* dbhh = (const float*)d_in[base+11];
  const float* pw   = (const float*)d_in[base+12];
  const float* pb   = (const float*)d_in[base+13];
  const float* ow   = (const float*)d_in[base+14];
  const float* ob   = (const float*)d_in[base+15];
  float* wsf = (float*)d_ws;

  // ws-adaptive chunk length: stage (chunkLen*NBLK*2048 fp32) + state (8 MB)
  size_t wsFloats = ws_size / 4;
  size_t avail = (wsFloats > STATE_FLOATS) ? (wsFloats - STATE_FLOATS) : 0;
  int chunkLen = (int)(avail / ((size_t)NBLK * 2048));
  if (chunkLen > 50) chunkLen = 50;
  if (chunkLen < 1)  chunkLen = 1;
  unsigned long long stageFloats = (unsigned long long)chunkLen * NBLK * 2048;

  hipFuncSetAttribute((const void*)k_l0,  hipFuncAttributeMaxDynamicSharedMemorySize, LDS_A);
  hipFuncSetAttribute((const void*)k_l1,  hipFuncAttributeMaxDynamicSharedMemorySize, LDS_C);
  hipFuncSetAttribute((const void*)k_dec, hipFuncAttributeMaxDynamicSharedMemorySize, LDS_D);

  for (int k0 = 0; k0 < TSTEPS; k0 += chunkLen){
    int len = chunkLen; if (k0 + len > TSTEPS) len = TSTEPS - k0;
    k_l0<<<NBLK,512,LDS_A,stream>>>(xh, wih0, whh0, bih0, bhh0, wsf, k0, len, stageFloats);
    k_l1<<<NBLK,512,LDS_C,stream>>>(wih1, whh1, bih1, bhh1, wsf, k0, len, stageFloats);
  }
  k_dec<<<NBLK,512,LDS_D,stream>>>(xh, prm, dwih, dwhh, dbih, dbhh,
                                   pw, pb, ow, ob, wsf, (float*)d_out, stageFloats);
}